// Round 10
// baseline (91405.682 us; speedup 1.0000x reference)
//
#include <hip/hip_runtime.h>

typedef unsigned int u32;
typedef _Float16 half_t;
typedef _Float16 half2_t __attribute__((ext_vector_type(2)));

#define B_ 64
#define T_ 2048
#define I_ 128
#define H_ 512
#define O_ 128

static __device__ __forceinline__ float dot2w(u32 w, u32 h, float acc) {
  return __builtin_amdgcn_fdot2(__builtin_bit_cast(half2_t, w),
                                __builtin_bit_cast(half2_t, h), acc, false);
}

// ---------------- K1: pack weights + init hg[0] + zero counters ----------------
// Whh_pk (4-CU layout): uint4 index (s*16 + f)*512 + l, f = rs*8 + m4.
//   block slice s owns rows [s*128, s*128+128); lane l: row pair p=l>>3,
//   rows s*128+2p+rs, k-chunk g=l&7 -> k0 = g*64 + m4*8 + w*2.
__global__ void k_prep(const float* __restrict__ Whh, const float* __restrict__ Mhh,
                       const float* __restrict__ Wih, const float* __restrict__ Mih,
                       const float* __restrict__ Wfc, const float* __restrict__ h0,
                       u32* __restrict__ Whh_pk, u32* __restrict__ Wih_pk,
                       u32* __restrict__ Wfc_pk, u32* __restrict__ hg,
                       u32* __restrict__ cnt) {
  int idx = blockIdx.x * 256 + threadIdx.x;
  if (idx < 131072) {
    int w = idx & 3, q = idx >> 2;
    int l = q & 511, sf = q >> 9;
    int s = sf >> 4, f = sf & 15;
    int rs = f >> 3, m4 = f & 7;
    int row = s * 128 + ((l >> 3) << 1) + rs;
    int k0 = (l & 7) * 64 + m4 * 8 + w * 2;
    float a = Whh[row * 512 + k0]     * Mhh[row * 512 + k0];
    float b = Whh[row * 512 + k0 + 1] * Mhh[row * 512 + k0 + 1];
    half2_t hv = { (half_t)a, (half_t)b };
    Whh_pk[idx] = __builtin_bit_cast(u32, hv);
  } else if (idx < 131072 + 32768) {
    int i2 = idx - 131072;
    int h = i2 >> 6, w = i2 & 63;
    int k0 = w * 2;
    float a = Wih[h * 128 + k0]     * Mih[h * 128 + k0];
    float b = Wih[h * 128 + k0 + 1] * Mih[h * 128 + k0 + 1];
    half2_t hv = { (half_t)a, (half_t)b };
    Wih_pk[h * 64 + w] = __builtin_bit_cast(u32, hv);
  } else if (idx < 196608) {
    int i3 = idx - 163840;
    int o = i3 >> 8, w = i3 & 255;
    float a = Wfc[o * 512 + 2 * w];
    float b = Wfc[o * 512 + 2 * w + 1];
    half2_t hv = { (half_t)a, (half_t)b };
    Wfc_pk[o * 256 + w] = __builtin_bit_cast(u32, hv);
  } else if (idx < 196608 + 16384) {
    int i4 = idx - 196608;
    int b = i4 >> 8, w = i4 & 255;
    float a = h0[b * 512 + 2 * w];
    float c = h0[b * 512 + 2 * w + 1];
    half2_t hv = { (half_t)a, (half_t)c };
    hg[b * 256 + w] = __builtin_bit_cast(u32, hv);   // hg[par=0]
  } else if (idx < 196608 + 16384 + 1024) {
    cnt[idx - 212992] = 0;
  }
}

// ---------------- K2: xproj[b][t][h] = x . Wih_m^T + b_ih + b_hh (fp16 out) ----
__launch_bounds__(512, 2)
__global__ void k_xproj(const float* __restrict__ x, const u32* __restrict__ Wih_pk,
                        const float* __restrict__ b_ih, const float* __restrict__ b_hh,
                        half_t* __restrict__ xp) {
  const int l = threadIdx.x;           // l = h
  const int r0 = blockIdx.x * 256;     // 256 (b,t) rows per block
  __shared__ u32 xb[2][64];
  u32 W[64];
#pragma unroll
  for (int i = 0; i < 16; ++i)
    *(uint4*)&W[i * 4] = *(const uint4*)(Wih_pk + l * 64 + i * 4);
  const float bs = b_ih[l] + b_hh[l];

  float2 g = { 0.f, 0.f };
  if (l < 64) {
    g = *(const float2*)(x + (size_t)r0 * 128 + 2 * l);
    half2_t hv = { (half_t)g.x, (half_t)g.y };
    xb[0][l] = __builtin_bit_cast(u32, hv);
    g = *(const float2*)(x + (size_t)(r0 + 1) * 128 + 2 * l);
  }
  __syncthreads();
  for (int i = 0; i < 256; ++i) {
    if (l < 64 && i + 1 < 256) {
      half2_t hv = { (half_t)g.x, (half_t)g.y };
      xb[(i + 1) & 1][l] = __builtin_bit_cast(u32, hv);
      int nf = (i + 2 < 256) ? i + 2 : i + 1;
      g = *(const float2*)(x + (size_t)(r0 + nf) * 128 + 2 * l);
    }
    float a0 = 0.f, a1 = 0.f;
#pragma unroll
    for (int m = 0; m < 16; ++m) {
      uint4 hv = *(const uint4*)&xb[i & 1][m * 4];
      a0 = dot2w(W[m * 4 + 0], hv.x, a0);
      a1 = dot2w(W[m * 4 + 1], hv.y, a1);
      a0 = dot2w(W[m * 4 + 2], hv.z, a0);
      a1 = dot2w(W[m * 4 + 3], hv.w, a1);
    }
    xp[(size_t)(r0 + i) * 512 + l] = (half_t)(a0 + a1 + bs);
    __syncthreads();
  }
}

// ---------------- K3: recurrence, FOUR blocks per batch (256 blocks total) ----
// Block bid: batch b=bid&63, slice s=bid>>6 -> rows [s*128, s*128+128).
// 128 KB weights/CU = 64 u32/lane = 16 named uint4 frags -> fully register-
// resident WITHIN the allocator's 128-reg budget (no launder needed; r2-r9
// showed spill/remat only when demand > budget). Zero LDS, zero weight stream.
// Per-step cross-CU rendezvous: agent-scope h stores -> barrier -> lane0
// fetch_add(RELEASE) on cnt[b] -> all waves spin load(ACQUIRE) >= 4(t+1).
// Correct under any XCD placement (agent scope); co-residency guaranteed by
// grid=256 blocks <= capacity (2 blocks/CU at 128 VGPR).
// hs aliases xp: word (b*2048+t)*256 + s*64 + p is read (xproj) then
// overwritten (h) by the same lane in the same step.
#define WPLD(N, F) u32 N##_x, N##_y, N##_z, N##_w; \
  { uint4 t_ = wpk4[(F) * 512]; \
    N##_x = t_.x; N##_y = t_.y; N##_z = t_.z; N##_w = t_.w; }
#define DOTQ(accv, N, H) { accv = dot2w(N##_x, (H).x, accv); accv = dot2w(N##_y, (H).y, accv); \
                           accv = dot2w(N##_z, (H).z, accv); accv = dot2w(N##_w, (H).w, accv); }

__global__ void __launch_bounds__(512)
k_rec(const u32* __restrict__ Whh_pk, half_t* __restrict__ xp,
      u32* __restrict__ hg, u32* __restrict__ cnt) {
  const int bid = blockIdx.x;
  const int b = bid & 63, s = bid >> 6;
  const int l = threadIdx.x;
  const int g = l & 7;                    // k-chunk [g*64, g*64+64)
  const int p = l >> 3;                   // row pair within slice [0,64)
  const int b0 = l & 1;

  const uint4* wpk4 = (const uint4*)Whh_pk + (size_t)s * 16 * 512 + l;
  // 16 register-resident frags: W<rs>_<m4>
  WPLD(W0_0, 0)  WPLD(W0_1, 1)  WPLD(W0_2, 2)  WPLD(W0_3, 3)
  WPLD(W0_4, 4)  WPLD(W0_5, 5)  WPLD(W0_6, 6)  WPLD(W0_7, 7)
  WPLD(W1_0, 8)  WPLD(W1_1, 9)  WPLD(W1_2, 10) WPLD(W1_3, 11)
  WPLD(W1_4, 12) WPLD(W1_5, 13) WPLD(W1_6, 14) WPLD(W1_7, 15)

  u32* cntp = cnt + b * 16;
  const uint4* hgb = (const uint4*)hg + b * 64 + g * 8;   // + par*4096
  u32* xpw = (u32*)xp;
  const size_t xpbase = ((size_t)b * 2048) * 256 + s * 64 + p;
  const int hgst = b * 256 + s * 64 + p;                  // + (par^1)*16384

  for (int t = 0; t < T_; ++t) {
    const int par = t & 1;
    const uint4* hp = hgb + par * 4096;
    uint4 hA0 = hp[0], hA1 = hp[1], hA2 = hp[2], hA3 = hp[3];
    uint4 hA4 = hp[4], hA5 = hp[5], hA6 = hp[6], hA7 = hp[7];
    u32 xw = xpw[xpbase + (size_t)t * 256];   // xproj word for rows {2p,2p+1}

    float a0 = 0.f, a1 = 0.f;
    DOTQ(a0, W0_0, hA0) DOTQ(a1, W1_0, hA0)
    DOTQ(a0, W0_1, hA1) DOTQ(a1, W1_1, hA1)
    DOTQ(a0, W0_2, hA2) DOTQ(a1, W1_2, hA2)
    DOTQ(a0, W0_3, hA3) DOTQ(a1, W1_3, hA3)
    DOTQ(a0, W0_4, hA4) DOTQ(a1, W1_4, hA4)
    DOTQ(a0, W0_5, hA5) DOTQ(a1, W1_5, hA5)
    DOTQ(a0, W0_6, hA6) DOTQ(a1, W1_6, hA6)
    DOTQ(a0, W0_7, hA7) DOTQ(a1, W1_7, hA7)

    // keep-half level (rows) then plain adds (k-chunks); lane -> row 2p+b0
    float keep = b0 ? a1 : a0;
    float send = b0 ? a0 : a1;
    float s1v = keep + __shfl_xor(send, 1, 64);
    s1v += __shfl_xor(s1v, 2, 64);
    s1v += __shfl_xor(s1v, 4, 64);

    float xpf = (float)__builtin_bit_cast(half_t,
                  (unsigned short)(b0 ? (xw >> 16) : (xw & 0xffff)));
    float sarg = s1v + xpf;
    float ax = fabsf(sarg);
    float e = __expf(-2.f * ax);
    float r = (1.f - e) * __builtin_amdgcn_rcpf(1.f + e);
    float hval = copysignf(r, sarg);
    half_t hv = (half_t)hval;

    u32 hvb = (u32)__builtin_bit_cast(unsigned short, hv);
    u32 oth = (u32)__shfl_xor((int)hvb, 1, 64);     // g0 <- g1's row 2p+1
    if (g == 0) {
      u32 packed = hvb | (oth << 16);
      xpw[xpbase + (size_t)t * 256] = packed;       // hs history (plain)
      __hip_atomic_store(&hg[(par ^ 1) * 16384 + hgst], packed,
                         __ATOMIC_RELAXED, __HIP_MEMORY_SCOPE_AGENT);
    }
    __syncthreads();                                // all stores drained
    if (l == 0)
      __hip_atomic_fetch_add(cntp, 1u, __ATOMIC_RELEASE, __HIP_MEMORY_SCOPE_AGENT);
    const u32 tgt = 4u * (u32)(t + 1);
    while (__hip_atomic_load(cntp, __ATOMIC_ACQUIRE, __HIP_MEMORY_SCOPE_AGENT) < tgt)
      __builtin_amdgcn_s_sleep(1);
    __syncthreads();
  }
}

// ---------------- K4: readout out[b][t][o] = hs . Wfc^T + b_fc ----------------
__launch_bounds__(256, 2)
__global__ void k_fc(const half_t* __restrict__ hs, const u32* __restrict__ Wfc_pk,
                     const float* __restrict__ b_fc, float* __restrict__ out) {
  const int l = threadIdx.x;
  const int w = l >> 6;                       // wave 0..3
  const int o = (l & 31) + w * 32;
  const int kh = (l >> 5) & 1;                // k half
  const int r0 = blockIdx.x * 256;
  __shared__ u32 sb[2][256];
  u32 W[128];
#pragma unroll
  for (int i = 0; i < 32; ++i)
    *(uint4*)&W[i * 4] = *(const uint4*)(Wfc_pk + o * 256 + kh * 128 + i * 4);
  const float bf = b_fc[o];
  const u32* hsw = (const u32*)hs;

  u32 gA = hsw[(size_t)r0 * 256 + l];
  sb[0][l] = gA;
  gA = hsw[(size_t)(r0 + 1) * 256 + l];
  __syncthreads();
  for (int i = 0; i < 256; ++i) {
    if (i + 1 < 256) {
      sb[(i + 1) & 1][l] = gA;
      int nf = (i + 2 < 256) ? i + 2 : i + 1;
      gA = hsw[(size_t)(r0 + nf) * 256 + l];
    }
    float a0 = 0.f, a1 = 0.f;
#pragma unroll
    for (int m = 0; m < 32; ++m) {
      uint4 hv = *(const uint4*)&sb[i & 1][kh * 128 + m * 4];
      a0 = dot2w(W[m * 4 + 0], hv.x, a0);
      a1 = dot2w(W[m * 4 + 1], hv.y, a1);
      a0 = dot2w(W[m * 4 + 2], hv.z, a0);
      a1 = dot2w(W[m * 4 + 3], hv.w, a1);
    }
    float a = a0 + a1;
    a += __shfl_xor(a, 32, 64);
    if (kh == 0) out[(size_t)(r0 + i) * 128 + o] = a + bf;
    __syncthreads();
  }
}

extern "C" void kernel_launch(void* const* d_in, const int* in_sizes, int n_in,
                              void* d_out, int out_size, void* d_ws, size_t ws_size,
                              hipStream_t stream) {
  const float* x   = (const float*)d_in[0];
  const float* h0  = (const float*)d_in[1];
  const float* Wih = (const float*)d_in[2];
  const float* bih = (const float*)d_in[3];
  const float* Whh = (const float*)d_in[4];
  const float* bhh = (const float*)d_in[5];
  const float* Mih = (const float*)d_in[6];
  const float* Mhh = (const float*)d_in[7];
  const float* Wfc = (const float*)d_in[8];
  const float* bfc = (const float*)d_in[9];
  float* out = (float*)d_out;

  char* ws = (char*)d_ws;
  // layout (~135.1 MB):
  //   xproj/hs fp16 (128 MB) | Whh_pk 512K | Wih_pk 128K | Wfc_pk 128K |
  //   hg ping-pong 128K | cnt 4K
  half_t* xproj = (half_t*)(ws);                       // aliased: becomes hs
  u32* Whh_pk = (u32*)(ws + 134217728);
  u32* Wih_pk = (u32*)(ws + 134742016);
  u32* Wfc_pk = (u32*)(ws + 134873088);
  u32* hg     = (u32*)(ws + 135004160);
  u32* cnt    = (u32*)(ws + 135135232);

  hipLaunchKernelGGL(k_prep, dim3(837), dim3(256), 0, stream,
                     Whh, Mhh, Wih, Mih, Wfc, h0, Whh_pk, Wih_pk, Wfc_pk, hg, cnt);
  hipLaunchKernelGGL(k_xproj, dim3(512), dim3(512), 0, stream,
                     x, Wih_pk, bih, bhh, xproj);
  hipLaunchKernelGGL(k_rec, dim3(256), dim3(512), 0, stream,
                     Whh_pk, xproj, hg, cnt);
  hipLaunchKernelGGL(k_fc, dim3(512), dim3(256), 0, stream,
                     xproj, Wfc_pk, bfc, out);
}